// Round 7
// baseline (156.562 us; speedup 1.0000x reference)
//
#include <hip/hip_runtime.h>
#include <hip/hip_bf16.h>
#include <math.h>

// FeedForwardQuantum — single fused MFMA kernel (round 7).
//
// q closed form: c_w = cos(x[n,w]+rx[w]); q[n,0]=prod_{1..9}c; q[n,w]=prod_{0..w}c
// h   = relu(q @ w1^T + b1)   — GEMM1 on MFMA *inside* the K-loop:
//                               mfma(w1_frag, q^T_frag) -> h^T (C-layout),
//                               packed to bf16 into a WAVE-PRIVATE LDS tile
//                               (no barrier needed for A: producer==consumer).
// out = h @ w2^T + b2         — round-6 GEMM2: 128x128 tile, BK=64,
//                               B staged via global_load_lds w=16 with
//                               global-side XOR swizzle (verified 0-conflict).
// h never touches HBM. w1/b1 chunk frags load from L2 and drain at the
// existing barrier. XCD-grouped grid: bm fast-varying -> 4 bn-twins of each
// bm share an XCD's L2 for w2b.

typedef __attribute__((ext_vector_type(8))) short short8;
typedef __attribute__((ext_vector_type(4))) float fx4;

constexpr int EDIM = 512;
constexpr int FDIM = 2048;
constexpr int NQ   = 10;
constexpr int BK   = 64;
constexpr int NCH  = FDIM / BK;   // 32

__device__ __forceinline__ ushort f2bf(float f) {   // f32 -> bf16 RNE
    union { float f; unsigned u; } v; v.f = f;
    unsigned u = v.u + 0x7FFFu + ((v.u >> 16) & 1u);
    return (ushort)(u >> 16);
}
__device__ __forceinline__ unsigned bits2(__hip_bfloat162 h) {
    union { __hip_bfloat162 h; unsigned u; } v; v.h = h; return v.u;
}
__device__ __forceinline__ void gload_lds16(const void* g, void* l) {
    __builtin_amdgcn_global_load_lds(
        (const __attribute__((address_space(1))) void*)g,
        (__attribute__((address_space(3))) void*)l, 16, 0, 0);
}

// ---- prep: w2 -> bf16; w1 -> [FDIM][32] bf16 zero-padded ----
__global__ void prep(const float* __restrict__ w1, const float* __restrict__ w2,
                     ushort* __restrict__ w2b, ushort* __restrict__ w1p) {
    int gid = blockIdx.x * blockDim.x + threadIdx.x;
    int np  = gridDim.x * blockDim.x;
    for (int i = gid; i < EDIM * FDIM / 4; i += np) {
        float4 v = ((const float4*)w2)[i];
        ushort4 o; o.x = f2bf(v.x); o.y = f2bf(v.y); o.z = f2bf(v.z); o.w = f2bf(v.w);
        ((ushort4*)w2b)[i] = o;
    }
    for (int i = gid; i < FDIM * 32; i += np) {
        int r = i >> 5, c = i & 31;
        w1p[i] = (c < NQ) ? f2bf(w1[r * NQ + c]) : (ushort)0;
    }
}

__global__ __launch_bounds__(256, 2) void ffq2(
    const float* __restrict__ x,
    const float* __restrict__ rx,
    const float* __restrict__ b1,
    const float* __restrict__ b2,
    const ushort* __restrict__ w2b,   // [EDIM][FDIM] bf16
    const ushort* __restrict__ w1p,   // [FDIM][32] bf16, cols 10..31 = 0
    float* __restrict__ out)
{
    __shared__ ushort qs[128 * 32];    //  8 KB: q padded to K=32
    __shared__ ushort As[4 * 64 * 64]; // 32 KB: wave-private h tiles [tok][k]
    __shared__ ushort Bs[128 * BK];    // 16 KB: w2 tile [row][k], swizzled

    const int tid  = threadIdx.x;
    const int bm   = blockIdx.x;       // fast-varying -> bn-twins share an XCD
    const int bn   = blockIdx.y;
    const int m0   = bm * 128, n0 = bn * 128;
    const int wave = tid >> 6, lane = tid & 63;
    const int quad = lane >> 4, l16 = lane & 15;
    const int wm   = wave >> 1, wn = wave & 1;

    // ---- preamble: closed-form quantum layer -> qs ----
    if (tid < 128) {
        const float* xr = x + (size_t)(m0 + tid) * EDIM;
        float c[NQ], q[NQ];
        #pragma unroll
        for (int w = 0; w < NQ; ++w) c[w] = cosf(xr[w] + rx[w]);
        float p0 = c[1];
        #pragma unroll
        for (int w = 2; w < NQ; ++w) p0 *= c[w];
        q[0] = p0;
        float p = c[0];
        #pragma unroll
        for (int w = 1; w < NQ; ++w) { p *= c[w]; q[w] = p; }
        ushort* row = &qs[tid * 32];
        #pragma unroll
        for (int w = 0; w < NQ; ++w) row[w] = f2bf(q[w]);
        #pragma unroll
        for (int w = NQ; w < 32; ++w) row[w] = 0;
    }
    __syncthreads();

    // q^T B-frags for this wave's 64 tokens (B[k=quad*8+j][n=tok=l16])
    short8 qf[4];
    #pragma unroll
    for (int tt = 0; tt < 4; ++tt)
        qf[tt] = *(const short8*)&qs[(wm * 64 + tt * 16 + l16) * 32 + quad * 8];

    // ---- B (w2) staging: global-side XOR swizzle, round-6 verified ----
    const ushort* gB[4];
    #pragma unroll
    for (int u = 0; u < 4; ++u) {
        int row = u * 32 + (tid >> 3);
        gB[u] = w2b + (size_t)(n0 + row) * FDIM + ((tid & 7) ^ (row & 7)) * 8;
    }
    const int ldst = wave * 512;   // + u*2048 (ushorts); lane*16B implicit

    // ---- w1/b1 chunk-frag bases (global, L2-resident) ----
    const ushort* w1base = w1p + l16 * 32 + quad * 8;   // + (k0+ft*16)*32
    const float*  b1base = b1 + quad * 4;               // + k0 + ft*16

    // ---- A (h^T) wave-private LDS addressing ----
    // write (GEMM1 C-layout): tok = tt*16+l16, f-block = ft*2+(quad>>1),
    //   stored block = f-block ^ (tok&7), within-block half = (quad&1)*4
    // read (A-frag): tok = mt*16+l16, k-block hf*4+quad, same XOR
    const int awav = wave * 4096;
    const int swz  = l16 & 7;
    const int aw_qh = quad >> 1, aw_half = (quad & 1) * 4;

    fx4 acc[4][4];
    #pragma unroll
    for (int a = 0; a < 4; ++a)
        #pragma unroll
        for (int b = 0; b < 4; ++b) acc[a][b] = fx4{0.f, 0.f, 0.f, 0.f};

    for (int i = 0; i < NCH; ++i) {
        const int k0 = i * BK;

        // stage B tile (fire-and-forget), w1/b1 frags to VGPRs
        #pragma unroll
        for (int u = 0; u < 4; ++u) {
            gload_lds16(gB[u], &Bs[u * 2048 + ldst]);
            gB[u] += BK;
        }
        short8 w1f[4]; fx4 b1v[4];
        #pragma unroll
        for (int ft = 0; ft < 4; ++ft) {
            w1f[ft] = *(const short8*)&w1base[(size_t)(k0 + ft * 16) * 32];
            b1v[ft] = *(const fx4*)&b1base[k0 + ft * 16];
        }
        __syncthreads();   // drains vmcnt: Bs resident, w1f/b1v ready

        // GEMM1: h^T for this wave's 64 tokens x 64 k -> wave-private As
        #pragma unroll
        for (int ft = 0; ft < 4; ++ft)
            #pragma unroll
            for (int tt = 0; tt < 4; ++tt) {
                fx4 h = __builtin_amdgcn_mfma_f32_16x16x32_bf16(
                    w1f[ft], qf[tt], b1v[ft], 0, 0, 0);
                uint2 pk;
                pk.x = bits2(__float22bfloat162_rn(
                    make_float2(fmaxf(h[0], 0.f), fmaxf(h[1], 0.f))));
                pk.y = bits2(__float22bfloat162_rn(
                    make_float2(fmaxf(h[2], 0.f), fmaxf(h[3], 0.f))));
                *(uint2*)&As[awav + (tt * 16 + l16) * 64 +
                             (((ft * 2 + aw_qh) ^ swz) << 3) + aw_half] = pk;
            }

        // frags (A from own writes — lgkmcnt orders; B from Bs)
        short8 af[4][2], bf[4][2];
        #pragma unroll
        for (int t = 0; t < 4; ++t)
            #pragma unroll
            for (int hf = 0; hf < 2; ++hf) {
                const int blk = ((hf * 4 + quad) ^ swz) << 3;
                af[t][hf] = *(const short8*)&As[awav + (t * 16 + l16) * 64 + blk];
                bf[t][hf] = *(const short8*)&Bs[(wn * 64 + t * 16 + l16) * BK + blk];
            }

        #pragma unroll
        for (int hf = 0; hf < 2; ++hf)
            #pragma unroll
            for (int mt = 0; mt < 4; ++mt)
                #pragma unroll
                for (int nt = 0; nt < 4; ++nt)
                    acc[mt][nt] = __builtin_amdgcn_mfma_f32_16x16x32_bf16(
                        af[mt][hf], bf[nt][hf], acc[mt][nt], 0, 0, 0);
        __syncthreads();   // protect Bs from next stage
    }

    // ---- epilogue: + b2, C-layout (col=l16 -> n, row=quad*4+r -> m) ----
    float bb[4];
    #pragma unroll
    for (int nt = 0; nt < 4; ++nt) bb[nt] = b2[n0 + wn * 64 + nt * 16 + l16];
    #pragma unroll
    for (int mt = 0; mt < 4; ++mt) {
        const int mbase = m0 + wm * 64 + mt * 16 + quad * 4;
        #pragma unroll
        for (int nt = 0; nt < 4; ++nt) {
            const int n = n0 + wn * 64 + nt * 16 + l16;
            #pragma unroll
            for (int r = 0; r < 4; ++r)
                out[(size_t)(mbase + r) * EDIM + n] = acc[mt][nt][r] + bb[nt];
        }
    }
}

extern "C" void kernel_launch(void* const* d_in, const int* in_sizes, int n_in,
                              void* d_out, int out_size, void* d_ws, size_t ws_size,
                              hipStream_t stream) {
    const float* x  = (const float*)d_in[0];
    const float* rx = (const float*)d_in[1];
    const float* w1 = (const float*)d_in[2];
    const float* b1 = (const float*)d_in[3];
    const float* w2 = (const float*)d_in[4];
    const float* b2 = (const float*)d_in[5];
    float* out = (float*)d_out;

    // ws: [0, 2 MiB) w2 bf16; [2 MiB, +128 KiB) w1 padded bf16
    ushort* w2b = (ushort*)d_ws;
    ushort* w1p = (ushort*)((char*)d_ws + (size_t)EDIM * FDIM * 2);

    hipLaunchKernelGGL(prep, dim3(256), dim3(256), 0, stream, w1, w2, w2b, w1p);

    const int M = in_sizes[0] / EDIM;   // 16384
    hipLaunchKernelGGL(ffq2, dim3(M / 128, EDIM / 128), dim3(256), 0, stream,
                       x, rx, b1, b2, w2b, w1p, out);
}